// Round 4
// baseline (142.166 us; speedup 1.0000x reference)
//
#include <hip/hip_runtime.h>
#include <cstddef>

#define SS 2048
#define DD 128
#define NB 8
#define BM 32
#define BT 64

// ---------------- Kernel A: per-row projections ----------------
// a2[row] = (x_row . rsum) * (1/sqrt(128)) * log2(e)   (pre-folded for exp2)
// k[row]  = x_row . ent
__global__ __launch_bounds__(256) void prep_rows(
    const float* __restrict__ X, const float* __restrict__ rotp,
    const float* __restrict__ entp, float* __restrict__ a2out,
    float* __restrict__ kout) {
  const int wid = threadIdx.x >> 6;
  const int lane = threadIdx.x & 63;
  const int row = blockIdx.x * 4 + wid;
  const float* xr = X + (size_t)row * DD;
  const int e = lane * 2;
  const float2 xv = *reinterpret_cast<const float2*>(xr + e);
  const float r0 = rotp[e * 3 + 0] + rotp[e * 3 + 1] + rotp[e * 3 + 2];
  const float r1 = rotp[e * 3 + 3] + rotp[e * 3 + 4] + rotp[e * 3 + 5];
  float av = xv.x * r0 + xv.y * r1;
  float kv = xv.x * entp[e] + xv.y * entp[e + 1];
#pragma unroll
  for (int off = 32; off > 0; off >>= 1) {
    av += __shfl_xor(av, off, 64);
    kv += __shfl_xor(kv, off, 64);
  }
  if (lane == 0) {
    a2out[row] = av * (0.08838834764831845f * 1.4426950408889634f);
    kout[row] = kv;
  }
}

// ---------------- Kernel B: per-batch kmax / kmin ----------------
__global__ __launch_bounds__(256) void kminmax(const float* __restrict__ kvec,
                                               float* __restrict__ kmx,
                                               float* __restrict__ kmn) {
  const int b = blockIdx.x;
  const int tid = threadIdx.x;
  float mx = -1e30f, mn = 1e30f;
  for (int i = tid; i < SS; i += 256) {
    const float v = kvec[b * SS + i];
    mx = fmaxf(mx, v);
    mn = fminf(mn, v);
  }
#pragma unroll
  for (int off = 32; off > 0; off >>= 1) {
    mx = fmaxf(mx, __shfl_xor(mx, off, 64));
    mn = fminf(mn, __shfl_xor(mn, off, 64));
  }
  __shared__ float smx[4], smn[4];
  const int wid = tid >> 6, lane = tid & 63;
  if (lane == 0) { smx[wid] = mx; smn[wid] = mn; }
  __syncthreads();
  if (tid == 0) {
    mx = fmaxf(fmaxf(smx[0], smx[1]), fmaxf(smx[2], smx[3]));
    mn = fminf(fminf(smn[0], smn[1]), fminf(smn[2], smn[3]));
    kmx[b] = mx;
    kmn[b] = mn;
  }
}

// ---------------- Kernel C: fused softmax-weighted PV ----------------
// block: 256 thr. tx in [0,16): d = tx*8 ; ty in [0,4): s = ty*8 + r (r<8);
// tz in [0,4) (== wave id): t-quarter of each tile.
// generator role: sg = tid&31 (s row), tq = tid>>5 (t-eighth of tile).
__global__ __launch_bounds__(256) void attn_main(
    const float* __restrict__ X, const float* __restrict__ a2,
    const float* __restrict__ kvec, const float* __restrict__ kmx,
    const float* __restrict__ kmn, float* __restrict__ out) {
  __shared__ float xs[BT * DD];   // 32 KiB x tile [t][d]
  __shared__ float wt[BT * BM];   // 8 KiB  w tile [t][s]
  __shared__ float denp[8 * BM];  // 1 KiB  denominator partials [tq][s]

  const int tid = threadIdx.x;
  const int tx = tid & 15;
  const int ty = (tid >> 4) & 3;
  const int tz = tid >> 6;
  const int b = blockIdx.y;
  const int s0 = blockIdx.x * BM;

  const int sg = tid & 31;
  const int tq = tid >> 5;

  const float ga = a2[b * SS + s0 + sg];
  const float gm = fmaxf(ga * kmx[b], ga * kmn[b]);
  float gden = 0.0f;

  float acc[8][8];
#pragma unroll
  for (int r = 0; r < 8; ++r)
#pragma unroll
    for (int c = 0; c < 8; ++c) acc[r][c] = 0.0f;

  const float* xb = X + (size_t)b * SS * DD;
  const float* kb = kvec + b * SS;

  for (int t0 = 0; t0 < SS; t0 += BT) {
    __syncthreads();
    // stage x tile (coalesced float4)
#pragma unroll
    for (int rnd = 0; rnd < 8; ++rnd) {
      const int idx = rnd * 1024 + tid * 4;
      const float4 v = *reinterpret_cast<const float4*>(xb + t0 * DD + idx);
      *reinterpret_cast<float4*>(xs + idx) = v;
    }
    // generate w tile once per (s,t) + exact denominator partials
#pragma unroll
    for (int j = 0; j < 8; ++j) {
      const float kt = kb[t0 + tq * 8 + j];
      const float w = exp2f(fmaf(ga, kt, -gm));
      wt[(tq * 8 + j) * BM + sg] = w;
      gden += w;
    }
    __syncthreads();
    // accumulate my t-quarter
#pragma unroll 4
    for (int ti = 0; ti < 16; ++ti) {
      const int tl = tz * 16 + ti;
      const float4 x0 = *reinterpret_cast<const float4*>(xs + tl * DD + tx * 8);
      const float4 x1 = *reinterpret_cast<const float4*>(xs + tl * DD + tx * 8 + 4);
      const float4 w0 = *reinterpret_cast<const float4*>(wt + tl * BM + ty * 8);
      const float4 w1 = *reinterpret_cast<const float4*>(wt + tl * BM + ty * 8 + 4);
      const float xr[8] = {x0.x, x0.y, x0.z, x0.w, x1.x, x1.y, x1.z, x1.w};
      const float wr[8] = {w0.x, w0.y, w0.z, w0.w, w1.x, w1.y, w1.z, w1.w};
#pragma unroll
      for (int r = 0; r < 8; ++r)
#pragma unroll
        for (int c = 0; c < 8; ++c) acc[r][c] = fmaf(wr[r], xr[c], acc[r][c]);
    }
  }

  __syncthreads();
  denp[tq * BM + sg] = gden;

  // combine tz partials into tz==0, reusing xs (16 KiB needed)
  for (int p = 1; p < 4; ++p) {
    __syncthreads();
    if (tz == p) {
#pragma unroll
      for (int r = 0; r < 8; ++r) {
        const int sl = ty * 8 + r;
        *reinterpret_cast<float4*>(xs + sl * DD + tx * 8) =
            make_float4(acc[r][0], acc[r][1], acc[r][2], acc[r][3]);
        *reinterpret_cast<float4*>(xs + sl * DD + tx * 8 + 4) =
            make_float4(acc[r][4], acc[r][5], acc[r][6], acc[r][7]);
      }
    }
    __syncthreads();
    if (tz == 0) {
#pragma unroll
      for (int r = 0; r < 8; ++r) {
        const int sl = ty * 8 + r;
        const float4 v0 = *reinterpret_cast<const float4*>(xs + sl * DD + tx * 8);
        const float4 v1 = *reinterpret_cast<const float4*>(xs + sl * DD + tx * 8 + 4);
        acc[r][0] += v0.x; acc[r][1] += v0.y; acc[r][2] += v0.z; acc[r][3] += v0.w;
        acc[r][4] += v1.x; acc[r][5] += v1.y; acc[r][6] += v1.z; acc[r][7] += v1.w;
      }
    }
  }

  if (tz == 0) {
#pragma unroll
    for (int r = 0; r < 8; ++r) {
      const int sl = ty * 8 + r;
      float den = 0.0f;
#pragma unroll
      for (int q = 0; q < 8; ++q) den += denp[q * BM + sl];
      const float inv = 1.0f / den;
      float* orow = out + ((size_t)b * SS + s0 + sl) * DD + tx * 8;
      *reinterpret_cast<float4*>(orow) =
          make_float4(acc[r][0] * inv, acc[r][1] * inv, acc[r][2] * inv, acc[r][3] * inv);
      *reinterpret_cast<float4*>(orow + 4) =
          make_float4(acc[r][4] * inv, acc[r][5] * inv, acc[r][6] * inv, acc[r][7] * inv);
    }
  }
}

extern "C" void kernel_launch(void* const* d_in, const int* in_sizes, int n_in,
                              void* d_out, int out_size, void* d_ws, size_t ws_size,
                              hipStream_t stream) {
  const float* X = (const float*)d_in[0];
  const float* rotp = (const float*)d_in[1];
  const float* entp = (const float*)d_in[2];
  float* out = (float*)d_out;

  float* a2 = (float*)d_ws;        // NB*SS floats
  float* kv = a2 + NB * SS;        // NB*SS floats
  float* kmx = kv + NB * SS;       // NB floats
  float* kmn = kmx + NB;           // NB floats

  prep_rows<<<NB * SS / 4, 256, 0, stream>>>(X, rotp, entp, a2, kv);
  kminmax<<<NB, 256, 0, stream>>>(kv, kmx, kmn);
  dim3 grid(SS / BM, NB);
  attn_main<<<grid, 256, 0, stream>>>(X, a2, kv, kmx, kmn, out);
}

// Round 5
// 68.868 us; speedup vs baseline: 2.0643x; 2.0643x over previous
//
#include <hip/hip_runtime.h>
#include <cstddef>
#include <cstdint>

#define SS 2048
#define DD 128
#define NB 8

typedef __attribute__((ext_vector_type(8))) short short8;
typedef __attribute__((ext_vector_type(16))) float f32x16;

// ---- workspace layout (bytes) ----
#define WS_A2   0
#define WS_KV   (NB*SS*4)              // 65536
#define WS_KMX  (2*NB*SS*4)            // 131072
#define WS_KMN  (WS_KMX + 128)
#define WS_XHI  (WS_KMX + 1024)        // 132096 (16B aligned)
#define TILE_BYTES 32768               // 128 d x 128 t x 2B, swizzled
#define XARR_BYTES (NB*16*TILE_BYTES)  // 4 MiB
#define WS_XLO  (WS_XHI + XARR_BYTES)
#define WS_NEED (size_t)(WS_XLO + XARR_BYTES)

// ---------------- Kernel A: per-row projections ----------------
__global__ __launch_bounds__(256) void prep_rows(
    const float* __restrict__ X, const float* __restrict__ rotp,
    const float* __restrict__ entp, float* __restrict__ a2out,
    float* __restrict__ kout) {
  const int wid = threadIdx.x >> 6;
  const int lane = threadIdx.x & 63;
  const int row = blockIdx.x * 4 + wid;
  const float* xr = X + (size_t)row * DD;
  const int e = lane * 2;
  const float2 xv = *reinterpret_cast<const float2*>(xr + e);
  const float r0 = rotp[e * 3 + 0] + rotp[e * 3 + 1] + rotp[e * 3 + 2];
  const float r1 = rotp[e * 3 + 3] + rotp[e * 3 + 4] + rotp[e * 3 + 5];
  float av = xv.x * r0 + xv.y * r1;
  float kv = xv.x * entp[e] + xv.y * entp[e + 1];
#pragma unroll
  for (int off = 32; off > 0; off >>= 1) {
    av += __shfl_xor(av, off, 64);
    kv += __shfl_xor(kv, off, 64);
  }
  if (lane == 0) {
    a2out[row] = av * (0.08838834764831845f * 1.4426950408889634f);
    kout[row] = kv;
  }
}

// ---------------- Kernel B: per-batch kmax / kmin ----------------
__global__ __launch_bounds__(256) void kminmax(const float* __restrict__ kvec,
                                               float* __restrict__ kmx,
                                               float* __restrict__ kmn) {
  const int b = blockIdx.x;
  const int tid = threadIdx.x;
  float mx = -1e30f, mn = 1e30f;
  for (int i = tid; i < SS; i += 256) {
    const float v = kvec[b * SS + i];
    mx = fmaxf(mx, v);
    mn = fminf(mn, v);
  }
#pragma unroll
  for (int off = 32; off > 0; off >>= 1) {
    mx = fmaxf(mx, __shfl_xor(mx, off, 64));
    mn = fminf(mn, __shfl_xor(mn, off, 64));
  }
  __shared__ float smx[4], smn[4];
  const int wid = tid >> 6, lane = tid & 63;
  if (lane == 0) { smx[wid] = mx; smn[wid] = mn; }
  __syncthreads();
  if (tid == 0) {
    mx = fmaxf(fmaxf(smx[0], smx[1]), fmaxf(smx[2], smx[3]));
    mn = fminf(fminf(smn[0], smn[1]), fminf(smn[2], smn[3]));
    kmx[b] = mx;
    kmn[b] = mn;
  }
}

// ---------------- Kernel P: X -> bf16 hi/lo, transposed [d][t], swizzled ----
// Tile block (b,T): byte(d,tt) = d*256 + ((tt*2) ^ ((d&7)<<4)).
__global__ __launch_bounds__(256) void xsplit(const float* __restrict__ X,
                                              uint8_t* __restrict__ ws) {
  const int T = blockIdx.x >> 2;      // 0..15
  const int part = blockIdx.x & 3;    // 0..3
  const int b = blockIdx.y;
  const int tid = threadIdx.x;
  const float* xt = X + ((size_t)b * SS + T * 128) * DD;
  uint8_t* hiB = ws + WS_XHI + (size_t)(b * 16 + T) * TILE_BYTES;
  uint8_t* loB = ws + WS_XLO + (size_t)(b * 16 + T) * TILE_BYTES;
#pragma unroll
  for (int j = 0; j < 2; ++j) {
    const int chunk = part * 512 + j * 256 + tid;  // 0..2047
    const int d = chunk >> 4;                      // 0..127
    const int tg = chunk & 15;                     // 0..15
    unsigned int hi[4], lo[4];
#pragma unroll
    for (int q = 0; q < 4; ++q) {
      unsigned int h2[2], l2[2];
#pragma unroll
      for (int e = 0; e < 2; ++e) {
        const int tt = tg * 8 + q * 2 + e;
        const float v = xt[(size_t)tt * DD + d];
        const unsigned int ub = __float_as_uint(v);
        const unsigned int hb = (ub + 0x7fffu + ((ub >> 16) & 1u)) >> 16;
        const float hf = __uint_as_float(hb << 16);
        const unsigned int ul = __float_as_uint(v - hf);
        const unsigned int lb = (ul + 0x7fffu + ((ul >> 16) & 1u)) >> 16;
        h2[e] = hb; l2[e] = lb;
      }
      hi[q] = h2[0] | (h2[1] << 16);
      lo[q] = l2[0] | (l2[1] << 16);
    }
    const int off = d * 256 + ((tg * 16) ^ ((d & 7) << 4));
    *reinterpret_cast<uint4*>(hiB + off) = make_uint4(hi[0], hi[1], hi[2], hi[3]);
    *reinterpret_cast<uint4*>(loB + off) = make_uint4(lo[0], lo[1], lo[2], lo[3]);
  }
}

// ---------------- async global->LDS helper ----------------
typedef __attribute__((address_space(3))) unsigned int lds_u32;
typedef const __attribute__((address_space(1))) unsigned int glb_u32;
__device__ __forceinline__ void gload16(const void* g, void* l) {
  __builtin_amdgcn_global_load_lds((glb_u32*)g, (lds_u32*)l, 16, 0, 0);
}

// ---------------- Kernel C: MFMA softmax-weighted PV ----------------
// 256 blocks: b = blk&7 (XCD affinity), s-tile = blk>>3 (BM=64 rows).
// 8 waves: mh = w>>2 (32-row half), kq = w&3 (K quarter).
__global__ __launch_bounds__(512, 2) void attn_mfma(
    const uint8_t* __restrict__ wsr, const float* __restrict__ a2,
    const float* __restrict__ kvec, const float* __restrict__ kmx,
    const float* __restrict__ kmn, float* __restrict__ out) {
  __shared__ uint8_t smem[65536];  // [0,32K)=Xhi tile, [32K,64K)=Xlo tile
  const int tid = threadIdx.x;
  const int w = tid >> 6;
  const int lane = tid & 63;
  const int lm = lane & 31;
  const int h = lane >> 5;
  const int mh = w >> 2;
  const int kq = w & 3;
  const int blk = blockIdx.x;
  const int b = blk & 7;
  const int s0 = (blk >> 3) * 64;

  const float ga = a2[b * SS + s0 + mh * 32 + lm];
  const float gm = fmaxf(ga * kmx[b], ga * kmn[b]);
  float gden = 0.0f;

  f32x16 acc[4];
#pragma unroll
  for (int nt = 0; nt < 4; ++nt)
#pragma unroll
    for (int r = 0; r < 16; ++r) acc[nt][r] = 0.0f;

  const uint8_t* hiA = wsr + WS_XHI + (size_t)b * 16 * TILE_BYTES;
  const uint8_t* loA = wsr + WS_XLO + (size_t)b * 16 * TILE_BYTES;
  const float* kb = kvec + b * SS;

  for (int T = 0; T < 16; ++T) {
    const uint8_t* hT = hiA + T * TILE_BYTES;
    const uint8_t* lT = loA + T * TILE_BYTES;
#pragma unroll
    for (int i = 0; i < 4; ++i) {
      const int off = (w * 4 + i) * 1024;
      gload16(hT + off + lane * 16, smem + off);
      gload16(lT + off + lane * 16, smem + 32768 + off);
    }
    __syncthreads();  // drains vmcnt; tiles ready
#pragma unroll
    for (int kk = 0; kk < 2; ++kk) {
      const int tb = T * 128 + kq * 32 + kk * 16 + h * 8;
      const float4 k0 = *reinterpret_cast<const float4*>(kb + tb);
      const float4 k1 = *reinterpret_cast<const float4*>(kb + tb + 4);
      float wv[8];
      wv[0] = exp2f(fmaf(ga, k0.x, -gm)); wv[1] = exp2f(fmaf(ga, k0.y, -gm));
      wv[2] = exp2f(fmaf(ga, k0.z, -gm)); wv[3] = exp2f(fmaf(ga, k0.w, -gm));
      wv[4] = exp2f(fmaf(ga, k1.x, -gm)); wv[5] = exp2f(fmaf(ga, k1.y, -gm));
      wv[6] = exp2f(fmaf(ga, k1.z, -gm)); wv[7] = exp2f(fmaf(ga, k1.w, -gm));
      short8 whi, wlo;
#pragma unroll
      for (int j = 0; j < 8; ++j) {
        gden += wv[j];
        const unsigned int ub = __float_as_uint(wv[j]);
        const unsigned int hb = (ub + 0x7fffu + ((ub >> 16) & 1u)) >> 16;
        const float hf = __uint_as_float(hb << 16);
        const unsigned int ul = __float_as_uint(wv[j] - hf);
        const unsigned int lb = (ul + 0x7fffu + ((ul >> 16) & 1u)) >> 16;
        whi[j] = (short)hb;
        wlo[j] = (short)lb;
      }
      // B-frag: row = nt*32+lm, byte col0 = 64*kq+32*kk+16*h, swizzle ^((row&7)<<4)
      const int base = lm * 256 + ((kq * 64 + kk * 32 + h * 16) ^ ((lm & 7) << 4));
#pragma unroll
      for (int nt = 0; nt < 4; ++nt) {
        const int a = base + nt * 8192;
        const short8 bh = *reinterpret_cast<const short8*>(smem + a);
        const short8 bl = *reinterpret_cast<const short8*>(smem + 32768 + a);
        acc[nt] = __builtin_amdgcn_mfma_f32_32x32x16_bf16(whi, bh, acc[nt], 0, 0, 0);
        acc[nt] = __builtin_amdgcn_mfma_f32_32x32x16_bf16(whi, bl, acc[nt], 0, 0, 0);
        acc[nt] = __builtin_amdgcn_mfma_f32_32x32x16_bf16(wlo, bh, acc[nt], 0, 0, 0);
      }
    }
    __syncthreads();  // done reading before next stage overwrites
  }

  // ---- cross-wave combine (reuse LDS) ----
  float* comb = reinterpret_cast<float*>(smem);           // 64x128 f32 = 32 KiB
  float* dl = reinterpret_cast<float*>(smem + 32768);     // 8 waves x 32 rows
  gden += __shfl_xor(gden, 32, 64);
  if (lane < 32) dl[w * 32 + lane] = gden;
#pragma unroll
  for (int p = 0; p < 4; ++p) {
    if (kq == p) {
#pragma unroll
      for (int nt = 0; nt < 4; ++nt)
#pragma unroll
        for (int r = 0; r < 16; ++r) {
          const int rr = (r & 3) + 8 * (r >> 2) + 4 * h;
          const int idx = (mh * 32 + rr) * 128 + nt * 32 + lm;
          if (p == 0) comb[idx] = acc[nt][r];
          else comb[idx] += acc[nt][r];
        }
    }
    __syncthreads();
  }

  // ---- epilogue: divide by denominator, store ----
  const int r = tid >> 3;            // 0..63
  const int cg = (tid & 7) * 16;
  const int rm = r & 31, rh = r >> 5;
  const float den = dl[rh * 128 + rm] + dl[rh * 128 + 32 + rm] +
                    dl[rh * 128 + 64 + rm] + dl[rh * 128 + 96 + rm];
  const float inv = 1.0f / den;
  float* orow = out + ((size_t)b * SS + s0 + r) * DD + cg;
#pragma unroll
  for (int q = 0; q < 4; ++q) {
    float4 v = *reinterpret_cast<const float4*>(comb + r * 128 + cg + q * 4);
    v.x *= inv; v.y *= inv; v.z *= inv; v.w *= inv;
    *reinterpret_cast<float4*>(orow + q * 4) = v;
  }
}

// ---------------- fallback fp32 kernel (ws too small) ----------------
__global__ __launch_bounds__(256) void attn_main(
    const float* __restrict__ X, const float* __restrict__ a2,
    const float* __restrict__ kvec, const float* __restrict__ kmx,
    const float* __restrict__ kmn, float* __restrict__ out) {
  __shared__ float xs[64 * DD];
  __shared__ float wt[64 * 32];
  __shared__ float denp[8 * 32];
  const int tid = threadIdx.x;
  const int tx = tid & 15;
  const int ty = (tid >> 4) & 3;
  const int tz = tid >> 6;
  const int b = blockIdx.y;
  const int s0 = blockIdx.x * 32;
  const int sg = tid & 31;
  const int tq = tid >> 5;
  const float ga = a2[b * SS + s0 + sg];
  const float gm = fmaxf(ga * kmx[b], ga * kmn[b]);
  float gden = 0.0f;
  float acc[8][8];
#pragma unroll
  for (int r = 0; r < 8; ++r)
#pragma unroll
    for (int c = 0; c < 8; ++c) acc[r][c] = 0.0f;
  const float* xb = X + (size_t)b * SS * DD;
  const float* kb = kvec + b * SS;
  for (int t0 = 0; t0 < SS; t0 += 64) {
    __syncthreads();
#pragma unroll
    for (int rnd = 0; rnd < 8; ++rnd) {
      const int idx = rnd * 1024 + tid * 4;
      *reinterpret_cast<float4*>(xs + idx) =
          *reinterpret_cast<const float4*>(xb + t0 * DD + idx);
    }
#pragma unroll
    for (int j = 0; j < 8; ++j) {
      const float kt = kb[t0 + tq * 8 + j];
      const float wv = exp2f(fmaf(ga, kt, -gm));
      wt[(tq * 8 + j) * 32 + sg] = wv;
      gden += wv;
    }
    __syncthreads();
#pragma unroll 4
    for (int ti = 0; ti < 16; ++ti) {
      const int tl = tz * 16 + ti;
      const float4 x0 = *reinterpret_cast<const float4*>(xs + tl * DD + tx * 8);
      const float4 x1 = *reinterpret_cast<const float4*>(xs + tl * DD + tx * 8 + 4);
      const float4 w0 = *reinterpret_cast<const float4*>(wt + tl * 32 + ty * 8);
      const float4 w1 = *reinterpret_cast<const float4*>(wt + tl * 32 + ty * 8 + 4);
      const float xr[8] = {x0.x, x0.y, x0.z, x0.w, x1.x, x1.y, x1.z, x1.w};
      const float wr[8] = {w0.x, w0.y, w0.z, w0.w, w1.x, w1.y, w1.z, w1.w};
#pragma unroll
      for (int r = 0; r < 8; ++r)
#pragma unroll
        for (int c = 0; c < 8; ++c) acc[r][c] = fmaf(wr[r], xr[c], acc[r][c]);
    }
  }
  __syncthreads();
  denp[tq * 32 + sg] = gden;
  for (int p = 1; p < 4; ++p) {
    __syncthreads();
    if (tz == p) {
#pragma unroll
      for (int r = 0; r < 8; ++r) {
        const int sl = ty * 8 + r;
        *reinterpret_cast<float4*>(xs + sl * DD + tx * 8) =
            make_float4(acc[r][0], acc[r][1], acc[r][2], acc[r][3]);
        *reinterpret_cast<float4*>(xs + sl * DD + tx * 8 + 4) =
            make_float4(acc[r][4], acc[r][5], acc[r][6], acc[r][7]);
      }
    }
    __syncthreads();
    if (tz == 0) {
#pragma unroll
      for (int r = 0; r < 8; ++r) {
        const int sl = ty * 8 + r;
        const float4 v0 = *reinterpret_cast<const float4*>(xs + sl * DD + tx * 8);
        const float4 v1 = *reinterpret_cast<const float4*>(xs + sl * DD + tx * 8 + 4);
        acc[r][0] += v0.x; acc[r][1] += v0.y; acc[r][2] += v0.z; acc[r][3] += v0.w;
        acc[r][4] += v1.x; acc[r][5] += v1.y; acc[r][6] += v1.z; acc[r][7] += v1.w;
      }
    }
  }
  if (tz == 0) {
#pragma unroll
    for (int r = 0; r < 8; ++r) {
      const int sl = ty * 8 + r;
      float den = 0.0f;
#pragma unroll
      for (int q = 0; q < 8; ++q) den += denp[q * 32 + sl];
      const float inv = 1.0f / den;
      float* orow = out + ((size_t)b * SS + s0 + sl) * DD + tx * 8;
      *reinterpret_cast<float4*>(orow) =
          make_float4(acc[r][0] * inv, acc[r][1] * inv, acc[r][2] * inv, acc[r][3] * inv);
      *reinterpret_cast<float4*>(orow + 4) =
          make_float4(acc[r][4] * inv, acc[r][5] * inv, acc[r][6] * inv, acc[r][7] * inv);
    }
  }
}

extern "C" void kernel_launch(void* const* d_in, const int* in_sizes, int n_in,
                              void* d_out, int out_size, void* d_ws, size_t ws_size,
                              hipStream_t stream) {
  const float* X = (const float*)d_in[0];
  const float* rotp = (const float*)d_in[1];
  const float* entp = (const float*)d_in[2];
  float* out = (float*)d_out;
  uint8_t* ws = (uint8_t*)d_ws;

  float* a2 = (float*)(ws + WS_A2);
  float* kv = (float*)(ws + WS_KV);
  float* kmxp = (float*)(ws + WS_KMX);
  float* kmnp = (float*)(ws + WS_KMN);

  prep_rows<<<NB * SS / 4, 256, 0, stream>>>(X, rotp, entp, a2, kv);
  kminmax<<<NB, 256, 0, stream>>>(kv, kmxp, kmnp);
  if (ws_size >= WS_NEED) {
    xsplit<<<dim3(64, NB), 256, 0, stream>>>(X, ws);
    attn_mfma<<<256, 512, 0, stream>>>((const uint8_t*)ws, a2, kv, kmxp, kmnp, out);
  } else {
    attn_main<<<dim3(SS / 32, NB), 256, 0, stream>>>(X, a2, kv, kmxp, kmnp, out);
  }
}